// Round 8
// baseline (270.647 us; speedup 1.0000x reference)
//
#include <hip/hip_runtime.h>

typedef __attribute__((ext_vector_type(4))) float f32x4;
typedef __attribute__((ext_vector_type(8))) __bf16 bf16x8;
typedef __attribute__((ext_vector_type(4))) __bf16 bf16x4;
typedef __attribute__((ext_vector_type(4))) int i32x4;

#define SXE (26624 * 512)   // elems of one [b][v] matrix, b=(n,l,c): 64*13*32 rows x 512

// ---------------- prep: x[n][c][v][l] f32 -> Xv2[(n*13+l)*32+c][v] bf16 ----------------
__global__ __launch_bounds__(256)
void prep_x(const float* __restrict__ x, __bf16* __restrict__ Xv2) {
  const int vt = blockIdx.x, n = blockIdx.y, tid = threadIdx.x;
  __shared__ float Xs[32 * 209];   // [c][v*13+l] for 16 v, pitch 209 (odd)
  const float* src = x + ((size_t)n * 32) * 6656 + vt * 16 * 13;
  for (int i = tid; i < 32 * 208; i += 256) {
    const int c = i / 208, r = i - c * 208;
    Xs[c * 209 + r] = src[(size_t)c * 6656 + r];
  }
  __syncthreads();
  for (int j = tid; j < 416; j += 256) {   // (l,c) rows, 16-v chunks
    const int c = j & 31, l = j >> 5;
    bf16x8 o8[2];
    #pragma unroll
    for (int v = 0; v < 16; ++v) o8[v >> 3][v & 7] = (__bf16)Xs[c * 209 + v * 13 + l];
    __bf16* d = Xv2 + (((size_t)n * 13 + l) * 32 + c) * 512 + vt * 16;
    *(bf16x8*)d = o8[0];
    *(bf16x8*)(d + 8) = o8[1];
  }
}

__global__ __launch_bounds__(256)
void cast_A(const float* __restrict__ A, __bf16* __restrict__ Ab) {
  const int i = blockIdx.x * 256 + threadIdx.x;
  const float4 f = ((const float4*)A)[i];
  bf16x4 o;
  o[0] = (__bf16)f.x; o[1] = (__bf16)f.y; o[2] = (__bf16)f.z; o[3] = (__bf16)f.w;
  ((bf16x4*)Ab)[i] = o;
}

// ---------------- diffusion GEMM: D[b][w] = sum_v SRC[b][v] * A_s[w][v] ----------------
// R7 schedule, 128b x 256w tile (A-tile 256x64 = 32KB + data 128x64 = 16KB), XCD-swizzled 1D grid.
// NT = total w-tiles per bx (2) * s (3) = 6
__global__ __launch_bounds__(256)
void gemm_bf16(const __bf16* __restrict__ Ab, const __bf16* __restrict__ SRC,
               __bf16* __restrict__ DSTB, size_t srcStride, size_t dstStride, int cpx) {
  const int tid = threadIdx.x;
  const int lane = tid & 63, wave = tid >> 6, q = lane >> 4, r16 = lane & 15;

  // bijective XCD swizzle (m204; grid % 8 == 0): logical lg = bx*6 + s*2 + by
  const int bid = blockIdx.x;
  const int lg = (bid & 7) * cpx + (bid >> 3);
  const int bx = lg / 6, r6 = lg % 6, s = r6 >> 1, by = r6 & 1;

  const __bf16* Amat = Ab + (size_t)s * 512 * 512;
  const __bf16* B = SRC + (size_t)s * srcStride;
  __bf16* D = DSTB + (size_t)s * dstStride;

  const int W0 = by * 256, B0 = bx * 128;
  const int wm = wave >> 1, wn = wave & 1;   // wave covers b: wm*64+[0,64), w: wn*128+[0,128)

  __shared__ char gsm[49152];   // As 32KB (256 rows x 64k) + Bs 16KB (128 rows x 64k)
  char* As = gsm;
  char* Bs = gsm + 32768;

  f32x4 acc[4][8];
  #pragma unroll
  for (int m = 0; m < 4; ++m)
    #pragma unroll
    for (int n = 0; n < 8; ++n) acc[m][n] = {0.f, 0.f, 0.f, 0.f};

  const int srow = lane >> 3, spos = lane & 7;

  for (int kt = 0; kt < 8; ++kt) {
    const int k0 = kt * 64;
    #pragma unroll
    for (int i = 0; i < 12; ++i) {          // 48 slots x 1KB: 0-31 = A (w-rows), 32-47 = data (b-rows)
      const int slot = i * 4 + wave;
      const int rr = (slot & 31 & ~32) ;    // placeholder to keep pattern clear (unused)
      (void)rr;
      const int gc = spos ^ (((slot & 31) * 0 + (slot < 32 ? (slot * 8 + srow) : ((slot - 32) * 8 + srow))) & 7);
      const int row = (slot < 32) ? (slot * 8 + srow) : ((slot - 32) * 8 + srow);
      const __bf16* g = (slot < 32)
          ? Amat + (size_t)(W0 + row) * 512 + k0 + ((spos ^ (row & 7)) * 8)
          : B    + (size_t)(B0 + row) * 512 + k0 + ((spos ^ (row & 7)) * 8);
      (void)gc;
      char* ld = gsm + slot * 1024 + lane * 16;
      __builtin_amdgcn_global_load_lds((const __attribute__((address_space(1))) unsigned int*)g,
                                       (__attribute__((address_space(3))) unsigned int*)ld, 16, 0, 0);
    }
    __syncthreads();
    #pragma unroll
    for (int ks = 0; ks < 2; ++ks) {
      bf16x8 af[8], df[4];
      const int ch = ks * 4 + q;
      #pragma unroll
      for (int n = 0; n < 8; ++n) {                    // A_s frags: rows = w (within 256-row As)
        const int r = wn * 128 + n * 16 + r16;
        af[n] = *(const bf16x8*)(As + r * 128 + ((ch ^ (r & 7)) << 4));
      }
      #pragma unroll
      for (int m = 0; m < 4; ++m) {                    // data frags: rows = b (within 128-row Bs)
        const int r = wm * 64 + m * 16 + r16;
        df[m] = *(const bf16x8*)(Bs + r * 128 + ((ch ^ (r & 7)) << 4));
      }
      #pragma unroll
      for (int m = 0; m < 4; ++m)
        #pragma unroll
        for (int n = 0; n < 8; ++n)
          acc[m][n] = __builtin_amdgcn_mfma_f32_16x16x32_bf16(af[n], df[m], acc[m][n], 0, 0, 0);
    }
    __syncthreads();
  }

  // D: row = w = (lane>>4)*4+reg (+frag), col = b = lane&15 (+frag). 4 contig w (8B) per store.
  #pragma unroll
  for (int m = 0; m < 4; ++m) {
    const int b = B0 + wm * 64 + m * 16 + r16;
    #pragma unroll
    for (int n = 0; n < 8; ++n) {
      const int w = W0 + wn * 128 + n * 16 + q * 4;
      bf16x4 o4;
      o4[0] = (__bf16)acc[m][n][0]; o4[1] = (__bf16)acc[m][n][1];
      o4[2] = (__bf16)acc[m][n][2]; o4[3] = (__bf16)acc[m][n][3];
      *(bf16x4*)(D + (size_t)b * 512 + w) = o4;
    }
  }
}

// ---------------- temporal conv as MFMA, transpose via scalar LDS gathers (R7-verified) ----------------
__global__ __launch_bounds__(256)
void conv_kernel(const __bf16* __restrict__ Xv2, const __bf16* __restrict__ Y1,
                 const __bf16* __restrict__ Y2, const float* __restrict__ W,
                 const float* __restrict__ bias, float* __restrict__ y) {
  const int vt = blockIdx.x;   // 8 tiles of 64 v
  const int n  = blockIdx.y;
  const int tid = threadIdx.x;
  const int lane = tid & 63, wave = tid >> 6, q = lane >> 4, r16 = lane & 15;

  __shared__ char sm[59392];   // Hs [l(13)][c(32)][v(64)x2B] = 53248 + Ws 6144; Ds overlays Hs
  char* Ws = sm + 53248;

  const __bf16* gsrc[7] = {Xv2, Y1, Y2, Y1 + (size_t)SXE, Y2 + (size_t)SXE,
                           Y1 + 2 * (size_t)SXE, Y2 + 2 * (size_t)SXE};

  f32x4 acc[11][2];
  #pragma unroll
  for (int t = 0; t < 11; ++t) { acc[t][0] = {0,0,0,0}; acc[t][1] = {0,0,0,0}; }

  for (int g = 0; g < 7; ++g) {
    __syncthreads();
    const __bf16* src = gsrc[g] + ((size_t)n * 416) * 512 + vt * 64;
    #pragma unroll
    for (int it = 0; it < 13; ++it) {
      const int idx = it * 256 + tid;
      const int l = idx >> 8, rem = idx & 255, c = rem >> 3, h = rem & 7;
      i32x4 val = *(const i32x4*)(src + ((size_t)(l * 32 + c) << 9) + h * 8);
      *(i32x4*)(sm + l * 4096 + c * 128 + h * 16) = val;
    }
    for (int idx = tid; idx < 768; idx += 256) {
      const int f = idx >> 7, rem2 = idx & 127, lw = rem2 >> 1, half = rem2 & 1;
      const int kt = f >> 1, of = f & 1;
      const int o = of * 16 + (lw & 15);
      const int cc = g * 32 + (lw >> 4) * 8 + half * 4;
      bf16x4 w4;
      #pragma unroll
      for (int j = 0; j < 4; ++j)
        w4[j] = (__bf16)W[((size_t)o * 224 + cc + j) * 3 + kt];
      *(bf16x4*)(Ws + idx * 8) = w4;
    }
    __syncthreads();

    bf16x8 a8[13];
    const int gbase = q * 8 * 128 + (wave * 16 + r16) * 2;
    #pragma unroll
    for (int l = 0; l < 13; ++l) {
      bf16x8 a;
      #pragma unroll
      for (int j = 0; j < 8; ++j)
        a[j] = *(const __bf16*)(sm + l * 4096 + gbase + j * 128);
      a8[l] = a;
    }
    bf16x8 wf[6];
    #pragma unroll
    for (int f = 0; f < 6; ++f)
      wf[f] = *(const bf16x8*)(Ws + (f * 64 + lane) * 16);

    #pragma unroll
    for (int kt = 0; kt < 3; ++kt)
      #pragma unroll
      for (int of = 0; of < 2; ++of)
        #pragma unroll
        for (int t = 0; t < 11; ++t)
          acc[t][of] = __builtin_amdgcn_mfma_f32_16x16x32_bf16(a8[t + kt], wf[kt * 2 + of], acc[t][of], 0, 0, 0);
  }

  float* Ds = (float*)sm;
  const int o16 = lane & 15;
  for (int p = 0; p < 2; ++p) {
    __syncthreads();
    #pragma unroll
    for (int t = 0; t < 11; ++t) {
      const int vbase = wave * 16 + q * 4;
      #pragma unroll
      for (int rg = 0; rg < 4; ++rg)
        Ds[o16 * 708 + (vbase + rg) * 11 + t] = acc[t][p][rg];
    }
    __syncthreads();
    for (int i = 0; i < 11; ++i) {
      const int cg = tid + i * 256;
      const int oo = cg / 176, ch = cg - oo * 176;
      f32x4 v4 = *(const f32x4*)(Ds + oo * 708 + ch * 4);
      const float bo = bias[p * 16 + oo];
      v4[0] += bo; v4[1] += bo; v4[2] += bo; v4[3] += bo;
      float* yp = y + (((size_t)n * 32 + p * 16 + oo) * 512 + vt * 64) * 11 + ch * 4;
      *(f32x4*)yp = v4;
    }
  }
}

extern "C" void kernel_launch(void* const* d_in, const int* in_sizes, int n_in,
                              void* d_out, int out_size, void* d_ws, size_t ws_size,
                              hipStream_t stream) {
  (void)in_sizes; (void)n_in; (void)out_size; (void)ws_size;
  const float* x = (const float*)d_in[0];
  const float* A = (const float*)d_in[1];
  const float* W = (const float*)d_in[2];
  const float* b = (const float*)d_in[3];
  float* y = (float*)d_out;

  // ws: Xv2 (27.3 MB) + Y1 x3 (81.8) + Y2 x3 (81.8) + Ab (1.6) = 192.4 MB (known-good)
  char* ws = (char*)d_ws;
  const size_t SXB = (size_t)SXE * 2;
  __bf16* Xv2 = (__bf16*)ws;
  __bf16* Y1  = (__bf16*)(ws + SXB);
  __bf16* Y2  = (__bf16*)(ws + 4 * SXB);
  __bf16* Ab  = (__bf16*)(ws + 7 * SXB);

  cast_A<<<dim3(768), 256, 0, stream>>>(A, Ab);
  prep_x<<<dim3(32, 64), 256, 0, stream>>>(x, Xv2);
  // grid = 208 bx * 2 by * 3 s = 1248 (divisible by 8; cpx = 156)
  gemm_bf16<<<dim3(1248), 256, 0, stream>>>(Ab, Xv2, Y1, 0, (size_t)SXE, 156);
  gemm_bf16<<<dim3(1248), 256, 0, stream>>>(Ab, Y1, Y2, (size_t)SXE, (size_t)SXE, 156);
  conv_kernel<<<dim3(8, 64), 256, 0, stream>>>(Xv2, Y1, Y2, W, b, y);
}

// Round 9
// 232.143 us; speedup vs baseline: 1.1659x; 1.1659x over previous
//
#include <hip/hip_runtime.h>

typedef __attribute__((ext_vector_type(4))) float f32x4;
typedef __attribute__((ext_vector_type(8))) __bf16 bf16x8;
typedef __attribute__((ext_vector_type(4))) __bf16 bf16x4;
typedef __attribute__((ext_vector_type(4))) int i32x4;

#define SXE (26624 * 512)   // elems of one [b][v] matrix, b=(n,l,c): 64*13*32 rows x 512

// ---------------- prep: x[n][c][v][l] f32 -> Xv2[(n*13+l)*32+c][v] bf16 ----------------
__global__ __launch_bounds__(256)
void prep_x(const float* __restrict__ x, __bf16* __restrict__ Xv2) {
  const int vt = blockIdx.x, n = blockIdx.y, tid = threadIdx.x;
  __shared__ float Xs[32 * 209];   // [c][v*13+l] for 16 v, pitch 209 (odd)
  const float* src = x + ((size_t)n * 32) * 6656 + vt * 16 * 13;
  for (int i = tid; i < 32 * 208; i += 256) {
    const int c = i / 208, r = i - c * 208;
    Xs[c * 209 + r] = src[(size_t)c * 6656 + r];
  }
  __syncthreads();
  for (int j = tid; j < 416; j += 256) {   // (l,c) rows, 16-v chunks
    const int c = j & 31, l = j >> 5;
    bf16x8 o8[2];
    #pragma unroll
    for (int v = 0; v < 16; ++v) o8[v >> 3][v & 7] = (__bf16)Xs[c * 209 + v * 13 + l];
    __bf16* d = Xv2 + (((size_t)n * 13 + l) * 32 + c) * 512 + vt * 16;
    *(bf16x8*)d = o8[0];
    *(bf16x8*)(d + 8) = o8[1];
  }
}

__global__ __launch_bounds__(256)
void cast_A(const float* __restrict__ A, __bf16* __restrict__ Ab) {
  const int i = blockIdx.x * 256 + threadIdx.x;
  const float4 f = ((const float4*)A)[i];
  bf16x4 o;
  o[0] = (__bf16)f.x; o[1] = (__bf16)f.y; o[2] = (__bf16)f.z; o[3] = (__bf16)f.w;
  ((bf16x4*)Ab)[i] = o;
}

// ---------------- diffusion GEMM (R7-verified structure, 128x128 tile) ----------------
// D[b][w] = sum_v SRC[b][v] * A_s[w][v]
// ONE change vs R7: 1-D grid with bijective XCD swizzle; logical lg = bx*12 + s*4 + by
// so the 12 blocks sharing a data-tile (bx) are contiguous on one XCD.
__global__ __launch_bounds__(256)
void gemm_bf16(const __bf16* __restrict__ Ab, const __bf16* __restrict__ SRC,
               __bf16* __restrict__ DSTB, size_t srcStride, size_t dstStride, int cpx) {
  const int tid = threadIdx.x;
  const int lane = tid & 63, wave = tid >> 6, q = lane >> 4;

  const int bid = blockIdx.x;
  const int lg = (bid & 7) * cpx + (bid >> 3);   // grid % 8 == 0 -> bijective (m204)
  const int bx = lg / 12, r12 = lg % 12, s = r12 >> 2, by = r12 & 3;

  const __bf16* Amat = Ab + (size_t)s * 512 * 512;
  const __bf16* B = SRC + (size_t)s * srcStride;
  __bf16* D = DSTB + (size_t)s * dstStride;

  const int W0 = by * 128, B0 = bx * 128;
  const int wm = wave >> 1, wn = wave & 1;

  __shared__ __bf16 As[128 * 64];
  __shared__ __bf16 Bs[128 * 64];

  f32x4 acc[4][4];
  #pragma unroll
  for (int m = 0; m < 4; ++m)
    #pragma unroll
    for (int n = 0; n < 4; ++n) acc[m][n] = {0.f, 0.f, 0.f, 0.f};

  const int srow = lane >> 3, spos = lane & 7;

  for (int kt = 0; kt < 8; ++kt) {
    const int k0 = kt * 64;
    #pragma unroll
    for (int i = 0; i < 4; ++i) {
      const int slot = i * 4 + wave;
      const int r = slot * 8 + srow;
      const int gc = spos ^ (r & 7);          // inverse-swizzled global source (rule 21)
      const __bf16* ga = Amat + (size_t)(W0 + r) * 512 + k0 + gc * 8;
      const __bf16* gb = B    + (size_t)(B0 + r) * 512 + k0 + gc * 8;
      char* la = (char*)As + slot * 1024 + lane * 16;
      char* lb = (char*)Bs + slot * 1024 + lane * 16;
      __builtin_amdgcn_global_load_lds((const __attribute__((address_space(1))) unsigned int*)ga,
                                       (__attribute__((address_space(3))) unsigned int*)la, 16, 0, 0);
      __builtin_amdgcn_global_load_lds((const __attribute__((address_space(1))) unsigned int*)gb,
                                       (__attribute__((address_space(3))) unsigned int*)lb, 16, 0, 0);
    }
    __syncthreads();
    #pragma unroll
    for (int ks = 0; ks < 2; ++ks) {
      bf16x8 af[4], df[4];
      const int ch = ks * 4 + q;
      #pragma unroll
      for (int m = 0; m < 4; ++m) {                    // A_s frags: rows = w
        const int r = wm * 64 + m * 16 + (lane & 15);
        af[m] = *(const bf16x8*)((const char*)As + r * 128 + ((ch ^ (r & 7)) << 4));
      }
      #pragma unroll
      for (int n = 0; n < 4; ++n) {                    // data frags: rows = b
        const int r = wn * 64 + n * 16 + (lane & 15);
        df[n] = *(const bf16x8*)((const char*)Bs + r * 128 + ((ch ^ (r & 7)) << 4));
      }
      #pragma unroll
      for (int m = 0; m < 4; ++m)
        #pragma unroll
        for (int n = 0; n < 4; ++n)
          acc[m][n] = __builtin_amdgcn_mfma_f32_16x16x32_bf16(af[m], df[n], acc[m][n], 0, 0, 0);
    }
    __syncthreads();
  }

  // D: col=lane&15 -> b, row=(lane>>4)*4+reg -> w. Store 4 consecutive w (8B) per lane.
  #pragma unroll
  for (int m = 0; m < 4; ++m) {
    const int w = W0 + wm * 64 + m * 16 + q * 4;
    #pragma unroll
    for (int n = 0; n < 4; ++n) {
      const int b = B0 + wn * 64 + n * 16 + (lane & 15);
      bf16x4 o4;
      o4[0] = (__bf16)acc[m][n][0]; o4[1] = (__bf16)acc[m][n][1];
      o4[2] = (__bf16)acc[m][n][2]; o4[3] = (__bf16)acc[m][n][3];
      *(bf16x4*)(D + (size_t)b * 512 + w) = o4;
    }
  }
}

// ---------------- temporal conv as MFMA, transpose via scalar LDS gathers (R7-verified) ----------------
__global__ __launch_bounds__(256)
void conv_kernel(const __bf16* __restrict__ Xv2, const __bf16* __restrict__ Y1,
                 const __bf16* __restrict__ Y2, const float* __restrict__ W,
                 const float* __restrict__ bias, float* __restrict__ y) {
  const int vt = blockIdx.x;   // 8 tiles of 64 v
  const int n  = blockIdx.y;
  const int tid = threadIdx.x;
  const int lane = tid & 63, wave = tid >> 6, q = lane >> 4, r16 = lane & 15;

  __shared__ char sm[59392];   // Hs [l(13)][c(32)][v(64)x2B] = 53248 + Ws 6144; Ds overlays Hs
  char* Ws = sm + 53248;

  const __bf16* gsrc[7] = {Xv2, Y1, Y2, Y1 + (size_t)SXE, Y2 + (size_t)SXE,
                           Y1 + 2 * (size_t)SXE, Y2 + 2 * (size_t)SXE};

  f32x4 acc[11][2];
  #pragma unroll
  for (int t = 0; t < 11; ++t) { acc[t][0] = {0,0,0,0}; acc[t][1] = {0,0,0,0}; }

  for (int g = 0; g < 7; ++g) {
    __syncthreads();
    const __bf16* src = gsrc[g] + ((size_t)n * 416) * 512 + vt * 64;
    #pragma unroll
    for (int it = 0; it < 13; ++it) {
      const int idx = it * 256 + tid;
      const int l = idx >> 8, rem = idx & 255, c = rem >> 3, h = rem & 7;
      i32x4 val = *(const i32x4*)(src + ((size_t)(l * 32 + c) << 9) + h * 8);
      *(i32x4*)(sm + l * 4096 + c * 128 + h * 16) = val;
    }
    for (int idx = tid; idx < 768; idx += 256) {
      const int f = idx >> 7, rem2 = idx & 127, lw = rem2 >> 1, half = rem2 & 1;
      const int kt = f >> 1, of = f & 1;
      const int o = of * 16 + (lw & 15);
      const int cc = g * 32 + (lw >> 4) * 8 + half * 4;
      bf16x4 w4;
      #pragma unroll
      for (int j = 0; j < 4; ++j)
        w4[j] = (__bf16)W[((size_t)o * 224 + cc + j) * 3 + kt];
      *(bf16x4*)(Ws + idx * 8) = w4;
    }
    __syncthreads();

    bf16x8 a8[13];
    const int gbase = q * 8 * 128 + (wave * 16 + r16) * 2;
    #pragma unroll
    for (int l = 0; l < 13; ++l) {
      bf16x8 a;
      #pragma unroll
      for (int j = 0; j < 8; ++j)
        a[j] = *(const __bf16*)(sm + l * 4096 + gbase + j * 128);
      a8[l] = a;
    }
    bf16x8 wf[6];
    #pragma unroll
    for (int f = 0; f < 6; ++f)
      wf[f] = *(const bf16x8*)(Ws + (f * 64 + lane) * 16);

    #pragma unroll
    for (int kt = 0; kt < 3; ++kt)
      #pragma unroll
      for (int of = 0; of < 2; ++of)
        #pragma unroll
        for (int t = 0; t < 11; ++t)
          acc[t][of] = __builtin_amdgcn_mfma_f32_16x16x32_bf16(a8[t + kt], wf[kt * 2 + of], acc[t][of], 0, 0, 0);
  }

  float* Ds = (float*)sm;
  const int o16 = lane & 15;
  for (int p = 0; p < 2; ++p) {
    __syncthreads();
    #pragma unroll
    for (int t = 0; t < 11; ++t) {
      const int vbase = wave * 16 + q * 4;
      #pragma unroll
      for (int rg = 0; rg < 4; ++rg)
        Ds[o16 * 708 + (vbase + rg) * 11 + t] = acc[t][p][rg];
    }
    __syncthreads();
    for (int i = 0; i < 11; ++i) {
      const int cg = tid + i * 256;
      const int oo = cg / 176, ch = cg - oo * 176;
      f32x4 v4 = *(const f32x4*)(Ds + oo * 708 + ch * 4);
      const float bo = bias[p * 16 + oo];
      v4[0] += bo; v4[1] += bo; v4[2] += bo; v4[3] += bo;
      float* yp = y + (((size_t)n * 32 + p * 16 + oo) * 512 + vt * 64) * 11 + ch * 4;
      *(f32x4*)yp = v4;
    }
  }
}

extern "C" void kernel_launch(void* const* d_in, const int* in_sizes, int n_in,
                              void* d_out, int out_size, void* d_ws, size_t ws_size,
                              hipStream_t stream) {
  (void)in_sizes; (void)n_in; (void)out_size; (void)ws_size;
  const float* x = (const float*)d_in[0];
  const float* A = (const float*)d_in[1];
  const float* W = (const float*)d_in[2];
  const float* b = (const float*)d_in[3];
  float* y = (float*)d_out;

  // ws: Xv2 (27.3 MB) + Y1 x3 (81.8) + Y2 x3 (81.8) + Ab (1.6) = 192.4 MB (known-good)
  char* ws = (char*)d_ws;
  const size_t SXB = (size_t)SXE * 2;
  __bf16* Xv2 = (__bf16*)ws;
  __bf16* Y1  = (__bf16*)(ws + SXB);
  __bf16* Y2  = (__bf16*)(ws + 4 * SXB);
  __bf16* Ab  = (__bf16*)(ws + 7 * SXB);

  cast_A<<<dim3(768), 256, 0, stream>>>(A, Ab);
  prep_x<<<dim3(32, 64), 256, 0, stream>>>(x, Xv2);
  // grid = 208 bx * 4 by * 3 s = 2496 = 8 * 312 (bijective swizzle; cpx = 312)
  gemm_bf16<<<dim3(2496), 256, 0, stream>>>(Ab, Xv2, Y1, 0, (size_t)SXE, 312);
  gemm_bf16<<<dim3(2496), 256, 0, stream>>>(Ab, Y1, Y2, (size_t)SXE, (size_t)SXE, 312);
  conv_kernel<<<dim3(8, 64), 256, 0, stream>>>(Xv2, Y1, Y2, W, b, y);
}

// Round 10
// 230.984 us; speedup vs baseline: 1.1717x; 1.0050x over previous
//
#include <hip/hip_runtime.h>

typedef __attribute__((ext_vector_type(4))) float f32x4;
typedef __attribute__((ext_vector_type(8))) __bf16 bf16x8;
typedef __attribute__((ext_vector_type(4))) __bf16 bf16x4;
typedef __attribute__((ext_vector_type(4))) int i32x4;

#define SXE (26624 * 512)   // elems of one [b][v] matrix, b=(n,l,c): 64*13*32 rows x 512

// ---------------- prep: x[n][c][v][l] f32 -> Xv2[(n*13+l)*32+c][v] bf16 ----------------
__global__ __launch_bounds__(256)
void prep_x(const float* __restrict__ x, __bf16* __restrict__ Xv2) {
  const int vt = blockIdx.x, n = blockIdx.y, tid = threadIdx.x;
  __shared__ float Xs[32 * 209];   // [c][v*13+l] for 16 v, pitch 209 (odd)
  const float* src = x + ((size_t)n * 32) * 6656 + vt * 16 * 13;
  for (int i = tid; i < 32 * 208; i += 256) {
    const int c = i / 208, r = i - c * 208;
    Xs[c * 209 + r] = src[(size_t)c * 6656 + r];
  }
  __syncthreads();
  for (int j = tid; j < 416; j += 256) {   // (l,c) rows, 16-v chunks
    const int c = j & 31, l = j >> 5;
    bf16x8 o8[2];
    #pragma unroll
    for (int v = 0; v < 16; ++v) o8[v >> 3][v & 7] = (__bf16)Xs[c * 209 + v * 13 + l];
    __bf16* d = Xv2 + (((size_t)n * 13 + l) * 32 + c) * 512 + vt * 16;
    *(bf16x8*)d = o8[0];
    *(bf16x8*)(d + 8) = o8[1];
  }
}

__global__ __launch_bounds__(256)
void cast_A(const float* __restrict__ A, __bf16* __restrict__ Ab) {
  const int i = blockIdx.x * 256 + threadIdx.x;
  const float4 f = ((const float4*)A)[i];
  bf16x4 o;
  o[0] = (__bf16)f.x; o[1] = (__bf16)f.y; o[2] = (__bf16)f.z; o[3] = (__bf16)f.w;
  ((bf16x4*)Ab)[i] = o;
}

// ---------------- diffusion GEMM: 256x256 tile, BK=64, 8 waves, dbuf LDS, issue-early ----------------
// D[b][w] = sum_v SRC[b][v] * A_s[w][v]
// wave (wm=wid>>2, wn=wid&3): b-rows wm*128+[0,128), w-rows wn*64+[0,64); 64 MFMA/K-step/wave.
// LDS (dynamic 128KB): buf{0,1} x (As 32KB | Bs 32KB). One barrier per K-step.
__global__ __launch_bounds__(512, 2)
void gemm_bf16(const __bf16* __restrict__ Ab, const __bf16* __restrict__ SRC,
               __bf16* __restrict__ DSTB, size_t srcStride, size_t dstStride, int cpx) {
  extern __shared__ char gsm[];
  const int tid = threadIdx.x;
  const int lane = tid & 63, wid = tid >> 6, q = lane >> 4, r16 = lane & 15;

  const int bid = blockIdx.x;
  const int lg = (bid & 7) * cpx + (bid >> 3);   // grid % 8 == 0 -> bijective (m204)
  const int bx = lg / 6, r6 = lg % 6, s = r6 >> 1, by = r6 & 1;

  const __bf16* Amat = Ab + (size_t)s * 512 * 512;
  const __bf16* B = SRC + (size_t)s * srcStride;
  __bf16* D = DSTB + (size_t)s * dstStride;

  const int W0 = by * 256, B0 = bx * 256;
  const int wm = wid >> 2, wn = wid & 3;
  const int srow = lane >> 3, spos = lane & 7;

  f32x4 acc[8][4];   // [df m (b-side)][af n (w-side)]
  #pragma unroll
  for (int m = 0; m < 8; ++m)
    #pragma unroll
    for (int n = 0; n < 4; ++n) acc[m][n] = {0.f, 0.f, 0.f, 0.f};

  // stage one K-step: A_s-tile (256 w-rows) + data-tile (256 b-rows), 32KB each
  auto STAGE = [&](int bufsel, int kt) {
    const int k0 = kt * 64;
    char* As = gsm + bufsel * 65536;
    char* Bs = As + 32768;
    #pragma unroll
    for (int i = 0; i < 4; ++i) {
      const int slot = i * 8 + wid;           // 32 slots x 1KB per tile
      const int r = slot * 8 + srow;          // tile row 0..255
      const int gc = spos ^ (r & 7);          // inverse-swizzled global source (rule 21)
      const __bf16* ga = Amat + (size_t)(W0 + r) * 512 + k0 + gc * 8;
      const __bf16* gb = B    + (size_t)(B0 + r) * 512 + k0 + gc * 8;
      __builtin_amdgcn_global_load_lds((const __attribute__((address_space(1))) unsigned int*)ga,
                                       (__attribute__((address_space(3))) unsigned int*)(As + slot * 1024 + lane * 16),
                                       16, 0, 0);
      __builtin_amdgcn_global_load_lds((const __attribute__((address_space(1))) unsigned int*)gb,
                                       (__attribute__((address_space(3))) unsigned int*)(Bs + slot * 1024 + lane * 16),
                                       16, 0, 0);
    }
  };

  STAGE(0, 0);
  __syncthreads();   // compiler emits per-wave vmcnt(0) before barrier -> buf0 visible

  for (int t = 0; t < 8; ++t) {
    const int cur = t & 1;
    if (t < 7) STAGE(cur ^ 1, t + 1);        // issue-early: drains only at end-of-iter barrier
    const char* As = gsm + cur * 65536;
    const char* Bs = As + 32768;
    #pragma unroll
    for (int ks = 0; ks < 2; ++ks) {
      const int ch = ks * 4 + q;
      bf16x8 af[4], df[8];
      #pragma unroll
      for (int n = 0; n < 4; ++n) {                    // A_s frags: rows = w
        const int r = wn * 64 + n * 16 + r16;
        af[n] = *(const bf16x8*)(As + r * 128 + ((ch ^ (r & 7)) << 4));
      }
      #pragma unroll
      for (int m = 0; m < 8; ++m) {                    // data frags: rows = b
        const int r = wm * 128 + m * 16 + r16;
        df[m] = *(const bf16x8*)(Bs + r * 128 + ((ch ^ (r & 7)) << 4));
      }
      __builtin_amdgcn_s_setprio(1);
      #pragma unroll
      for (int m = 0; m < 8; ++m)
        #pragma unroll
        for (int n = 0; n < 4; ++n)
          acc[m][n] = __builtin_amdgcn_mfma_f32_16x16x32_bf16(af[n], df[m], acc[m][n], 0, 0, 0);
      __builtin_amdgcn_s_setprio(0);
    }
    __syncthreads();   // drains this iter's staged loads; protects buf reuse
  }

  // D: row=w=(lane>>4)*4+reg (+frag), col=b=lane&15 (+frag). 4 contig w (8B) per store.
  #pragma unroll
  for (int m = 0; m < 8; ++m) {
    const int b = B0 + wm * 128 + m * 16 + r16;
    #pragma unroll
    for (int n = 0; n < 4; ++n) {
      const int w = W0 + wn * 64 + n * 16 + q * 4;
      bf16x4 o4;
      o4[0] = (__bf16)acc[m][n][0]; o4[1] = (__bf16)acc[m][n][1];
      o4[2] = (__bf16)acc[m][n][2]; o4[3] = (__bf16)acc[m][n][3];
      *(bf16x4*)(D + (size_t)b * 512 + w) = o4;
    }
  }
}

// ---------------- temporal conv as MFMA, transpose via scalar LDS gathers (R7-verified) ----------------
__global__ __launch_bounds__(256)
void conv_kernel(const __bf16* __restrict__ Xv2, const __bf16* __restrict__ Y1,
                 const __bf16* __restrict__ Y2, const float* __restrict__ W,
                 const float* __restrict__ bias, float* __restrict__ y) {
  const int vt = blockIdx.x;   // 8 tiles of 64 v
  const int n  = blockIdx.y;
  const int tid = threadIdx.x;
  const int lane = tid & 63, wave = tid >> 6, q = lane >> 4, r16 = lane & 15;

  __shared__ char sm[59392];   // Hs [l(13)][c(32)][v(64)x2B] = 53248 + Ws 6144; Ds overlays Hs
  char* Ws = sm + 53248;

  const __bf16* gsrc[7] = {Xv2, Y1, Y2, Y1 + (size_t)SXE, Y2 + (size_t)SXE,
                           Y1 + 2 * (size_t)SXE, Y2 + 2 * (size_t)SXE};

  f32x4 acc[11][2];
  #pragma unroll
  for (int t = 0; t < 11; ++t) { acc[t][0] = {0,0,0,0}; acc[t][1] = {0,0,0,0}; }

  for (int g = 0; g < 7; ++g) {
    __syncthreads();
    const __bf16* src = gsrc[g] + ((size_t)n * 416) * 512 + vt * 64;
    #pragma unroll
    for (int it = 0; it < 13; ++it) {
      const int idx = it * 256 + tid;
      const int l = idx >> 8, rem = idx & 255, c = rem >> 3, h = rem & 7;
      i32x4 val = *(const i32x4*)(src + ((size_t)(l * 32 + c) << 9) + h * 8);
      *(i32x4*)(sm + l * 4096 + c * 128 + h * 16) = val;
    }
    for (int idx = tid; idx < 768; idx += 256) {
      const int f = idx >> 7, rem2 = idx & 127, lw = rem2 >> 1, half = rem2 & 1;
      const int kt = f >> 1, of = f & 1;
      const int o = of * 16 + (lw & 15);
      const int cc = g * 32 + (lw >> 4) * 8 + half * 4;
      bf16x4 w4;
      #pragma unroll
      for (int j = 0; j < 4; ++j)
        w4[j] = (__bf16)W[((size_t)o * 224 + cc + j) * 3 + kt];
      *(bf16x4*)(Ws + idx * 8) = w4;
    }
    __syncthreads();

    bf16x8 a8[13];
    const int gbase = q * 8 * 128 + (wave * 16 + r16) * 2;
    #pragma unroll
    for (int l = 0; l < 13; ++l) {
      bf16x8 a;
      #pragma unroll
      for (int j = 0; j < 8; ++j)
        a[j] = *(const __bf16*)(sm + l * 4096 + gbase + j * 128);
      a8[l] = a;
    }
    bf16x8 wf[6];
    #pragma unroll
    for (int f = 0; f < 6; ++f)
      wf[f] = *(const bf16x8*)(Ws + (f * 64 + lane) * 16);

    #pragma unroll
    for (int kt = 0; kt < 3; ++kt)
      #pragma unroll
      for (int of = 0; of < 2; ++of)
        #pragma unroll
        for (int t = 0; t < 11; ++t)
          acc[t][of] = __builtin_amdgcn_mfma_f32_16x16x32_bf16(a8[t + kt], wf[kt * 2 + of], acc[t][of], 0, 0, 0);
  }

  float* Ds = (float*)sm;
  const int o16 = lane & 15;
  for (int p = 0; p < 2; ++p) {
    __syncthreads();
    #pragma unroll
    for (int t = 0; t < 11; ++t) {
      const int vbase = wave * 16 + q * 4;
      #pragma unroll
      for (int rg = 0; rg < 4; ++rg)
        Ds[o16 * 708 + (vbase + rg) * 11 + t] = acc[t][p][rg];
    }
    __syncthreads();
    for (int i = 0; i < 11; ++i) {
      const int cg = tid + i * 256;
      const int oo = cg / 176, ch = cg - oo * 176;
      f32x4 v4 = *(const f32x4*)(Ds + oo * 708 + ch * 4);
      const float bo = bias[p * 16 + oo];
      v4[0] += bo; v4[1] += bo; v4[2] += bo; v4[3] += bo;
      float* yp = y + (((size_t)n * 32 + p * 16 + oo) * 512 + vt * 64) * 11 + ch * 4;
      *(f32x4*)yp = v4;
    }
  }
}

extern "C" void kernel_launch(void* const* d_in, const int* in_sizes, int n_in,
                              void* d_out, int out_size, void* d_ws, size_t ws_size,
                              hipStream_t stream) {
  (void)in_sizes; (void)n_in; (void)out_size; (void)ws_size;
  const float* x = (const float*)d_in[0];
  const float* A = (const float*)d_in[1];
  const float* W = (const float*)d_in[2];
  const float* b = (const float*)d_in[3];
  float* y = (float*)d_out;

  // ws: Xv2 (27.3 MB) + Y1 x3 (81.8) + Y2 x3 (81.8) + Ab (1.6) = 192.4 MB (known-good)
  char* ws = (char*)d_ws;
  const size_t SXB = (size_t)SXE * 2;
  __bf16* Xv2 = (__bf16*)ws;
  __bf16* Y1  = (__bf16*)(ws + SXB);
  __bf16* Y2  = (__bf16*)(ws + 4 * SXB);
  __bf16* Ab  = (__bf16*)(ws + 7 * SXB);

  cast_A<<<dim3(768), 256, 0, stream>>>(A, Ab);
  prep_x<<<dim3(32, 64), 256, 0, stream>>>(x, Xv2);
  // grid = 104 bx * 2 by * 3 s = 624 = 8 * 78 (bijective swizzle; cpx = 78); 128KB dynamic LDS
  gemm_bf16<<<dim3(624), 512, 131072, stream>>>(Ab, Xv2, Y1, 0, (size_t)SXE, 78);
  gemm_bf16<<<dim3(624), 512, 131072, stream>>>(Ab, Y1, Y2, (size_t)SXE, (size_t)SXE, 78);
  conv_kernel<<<dim3(8, 64), 256, 0, stream>>>(Xv2, Y1, Y2, W, b, y);
}

// Round 11
// 228.062 us; speedup vs baseline: 1.1867x; 1.0128x over previous
//
#include <hip/hip_runtime.h>

typedef __attribute__((ext_vector_type(4))) float f32x4;
typedef __attribute__((ext_vector_type(8))) __bf16 bf16x8;
typedef __attribute__((ext_vector_type(4))) __bf16 bf16x4;
typedef __attribute__((ext_vector_type(4))) int i32x4;

#define SXE (26624 * 512)   // elems of one [b][v] matrix, b=(n,l,c): 64*13*32 rows x 512

// ---------------- prep: x[n][c][v][l] f32 -> Xv2[(n*13+l)*32+c][v] bf16 ----------------
__global__ __launch_bounds__(256)
void prep_x(const float* __restrict__ x, __bf16* __restrict__ Xv2) {
  const int vt = blockIdx.x, n = blockIdx.y, tid = threadIdx.x;
  __shared__ float Xs[32 * 209];   // [c][v*13+l] for 16 v, pitch 209 (odd)
  const float* src = x + ((size_t)n * 32) * 6656 + vt * 16 * 13;
  for (int i = tid; i < 32 * 208; i += 256) {
    const int c = i / 208, r = i - c * 208;
    Xs[c * 209 + r] = src[(size_t)c * 6656 + r];
  }
  __syncthreads();
  for (int j = tid; j < 416; j += 256) {   // (l,c) rows, 16-v chunks
    const int c = j & 31, l = j >> 5;
    bf16x8 o8[2];
    #pragma unroll
    for (int v = 0; v < 16; ++v) o8[v >> 3][v & 7] = (__bf16)Xs[c * 209 + v * 13 + l];
    __bf16* d = Xv2 + (((size_t)n * 13 + l) * 32 + c) * 512 + vt * 16;
    *(bf16x8*)d = o8[0];
    *(bf16x8*)(d + 8) = o8[1];
  }
}

__global__ __launch_bounds__(256)
void cast_A(const float* __restrict__ A, __bf16* __restrict__ Ab) {
  const int i = blockIdx.x * 256 + threadIdx.x;
  const float4 f = ((const float4*)A)[i];
  bf16x4 o;
  o[0] = (__bf16)f.x; o[1] = (__bf16)f.y; o[2] = (__bf16)f.z; o[3] = (__bf16)f.w;
  ((bf16x4*)Ab)[i] = o;
}

// ---------------- diffusion GEMM: 256x256 tile, BK=64, 8 waves, dbuf LDS, counted vmcnt ----------------
// D[b][w] = sum_v SRC[b][v] * A_s[w][v]
// R10 structure; ONE change: raw s_barrier + counted s_waitcnt vmcnt(8) (T4) instead of
// __syncthreads()'s vmcnt(0) drain. Loads get a full K-step to land.
__global__ __launch_bounds__(512, 2)
void gemm_bf16(const __bf16* __restrict__ Ab, const __bf16* __restrict__ SRC,
               __bf16* __restrict__ DSTB, size_t srcStride, size_t dstStride, int cpx) {
  extern __shared__ char gsm[];
  const int tid = threadIdx.x;
  const int lane = tid & 63, wid = tid >> 6, q = lane >> 4, r16 = lane & 15;

  const int bid = blockIdx.x;
  const int lg = (bid & 7) * cpx + (bid >> 3);   // grid % 8 == 0 -> bijective (m204)
  const int bx = lg / 6, r6 = lg % 6, s = r6 >> 1, by = r6 & 1;

  const __bf16* Amat = Ab + (size_t)s * 512 * 512;
  const __bf16* B = SRC + (size_t)s * srcStride;
  __bf16* D = DSTB + (size_t)s * dstStride;

  const int W0 = by * 256, B0 = bx * 256;
  const int wm = wid >> 2, wn = wid & 3;
  const int srow = lane >> 3, spos = lane & 7;

  f32x4 acc[8][4];   // [df m (b-side)][af n (w-side)]
  #pragma unroll
  for (int m = 0; m < 8; ++m)
    #pragma unroll
    for (int n = 0; n < 4; ++n) acc[m][n] = {0.f, 0.f, 0.f, 0.f};

  // stage one K-step: A_s-tile (256 w-rows) + data-tile (256 b-rows), 32KB each.
  // 8 global_load_lds per thread per call.
  auto STAGE = [&](int bufsel, int kt) {
    const int k0 = kt * 64;
    char* As = gsm + bufsel * 65536;
    char* Bs = As + 32768;
    #pragma unroll
    for (int i = 0; i < 4; ++i) {
      const int slot = i * 8 + wid;           // 32 slots x 1KB per tile
      const int r = slot * 8 + srow;          // tile row 0..255
      const int gc = spos ^ (r & 7);          // inverse-swizzled global source (rule 21)
      const __bf16* ga = Amat + (size_t)(W0 + r) * 512 + k0 + gc * 8;
      const __bf16* gb = B    + (size_t)(B0 + r) * 512 + k0 + gc * 8;
      __builtin_amdgcn_global_load_lds((const __attribute__((address_space(1))) unsigned int*)ga,
                                       (__attribute__((address_space(3))) unsigned int*)(As + slot * 1024 + lane * 16),
                                       16, 0, 0);
      __builtin_amdgcn_global_load_lds((const __attribute__((address_space(1))) unsigned int*)gb,
                                       (__attribute__((address_space(3))) unsigned int*)(Bs + slot * 1024 + lane * 16),
                                       16, 0, 0);
    }
  };

  STAGE(0, 0);   // oldest 8 loads
  STAGE(1, 1);   // next 8 (16 in flight)

  for (int t = 0; t < 8; ++t) {
    const int cur = t & 1;
    // wait for CURRENT buffer's loads only (oldest 8); newest 8 keep flying (T4).
    if (t < 7) asm volatile("s_waitcnt vmcnt(8)" ::: "memory");
    else       asm volatile("s_waitcnt vmcnt(0)" ::: "memory");
    asm volatile("s_barrier" ::: "memory");    // all waves: cur buffer fully landed

    const char* As = gsm + cur * 65536;
    const char* Bs = As + 32768;
    #pragma unroll
    for (int ks = 0; ks < 2; ++ks) {
      const int ch = ks * 4 + q;
      bf16x8 af[4], df[8];
      #pragma unroll
      for (int n = 0; n < 4; ++n) {                    // A_s frags: rows = w
        const int r = wn * 64 + n * 16 + r16;
        af[n] = *(const bf16x8*)(As + r * 128 + ((ch ^ (r & 7)) << 4));
      }
      #pragma unroll
      for (int m = 0; m < 8; ++m) {                    // data frags: rows = b
        const int r = wm * 128 + m * 16 + r16;
        df[m] = *(const bf16x8*)(Bs + r * 128 + ((ch ^ (r & 7)) << 4));
      }
      __builtin_amdgcn_s_setprio(1);
      #pragma unroll
      for (int m = 0; m < 8; ++m)
        #pragma unroll
        for (int n = 0; n < 4; ++n)
          acc[m][n] = __builtin_amdgcn_mfma_f32_16x16x32_bf16(af[n], df[m], acc[m][n], 0, 0, 0);
      __builtin_amdgcn_s_setprio(0);
    }

    asm volatile("s_barrier" ::: "memory");    // all waves done reading cur -> safe to re-stage
    if (t < 6) STAGE(cur, t + 2);
  }

  // D: row=w=(lane>>4)*4+reg (+frag), col=b=lane&15 (+frag). 4 contig w (8B) per store.
  #pragma unroll
  for (int m = 0; m < 8; ++m) {
    const int b = B0 + wm * 128 + m * 16 + r16;
    #pragma unroll
    for (int n = 0; n < 4; ++n) {
      const int w = W0 + wn * 64 + n * 16 + q * 4;
      bf16x4 o4;
      o4[0] = (__bf16)acc[m][n][0]; o4[1] = (__bf16)acc[m][n][1];
      o4[2] = (__bf16)acc[m][n][2]; o4[3] = (__bf16)acc[m][n][3];
      *(bf16x4*)(D + (size_t)b * 512 + w) = o4;
    }
  }
}

// ---------------- temporal conv as MFMA, transpose via scalar LDS gathers (R7-verified) ----------------
__global__ __launch_bounds__(256)
void conv_kernel(const __bf16* __restrict__ Xv2, const __bf16* __restrict__ Y1,
                 const __bf16* __restrict__ Y2, const float* __restrict__ W,
                 const float* __restrict__ bias, float* __restrict__ y) {
  const int vt = blockIdx.x;   // 8 tiles of 64 v
  const int n  = blockIdx.y;
  const int tid = threadIdx.x;
  const int lane = tid & 63, wave = tid >> 6, q = lane >> 4, r16 = lane & 15;

  __shared__ char sm[59392];   // Hs [l(13)][c(32)][v(64)x2B] = 53248 + Ws 6144; Ds overlays Hs
  char* Ws = sm + 53248;

  const __bf16* gsrc[7] = {Xv2, Y1, Y2, Y1 + (size_t)SXE, Y2 + (size_t)SXE,
                           Y1 + 2 * (size_t)SXE, Y2 + 2 * (size_t)SXE};

  f32x4 acc[11][2];
  #pragma unroll
  for (int t = 0; t < 11; ++t) { acc[t][0] = {0,0,0,0}; acc[t][1] = {0,0,0,0}; }

  for (int g = 0; g < 7; ++g) {
    __syncthreads();
    const __bf16* src = gsrc[g] + ((size_t)n * 416) * 512 + vt * 64;
    #pragma unroll
    for (int it = 0; it < 13; ++it) {
      const int idx = it * 256 + tid;
      const int l = idx >> 8, rem = idx & 255, c = rem >> 3, h = rem & 7;
      i32x4 val = *(const i32x4*)(src + ((size_t)(l * 32 + c) << 9) + h * 8);
      *(i32x4*)(sm + l * 4096 + c * 128 + h * 16) = val;
    }
    for (int idx = tid; idx < 768; idx += 256) {
      const int f = idx >> 7, rem2 = idx & 127, lw = rem2 >> 1, half = rem2 & 1;
      const int kt = f >> 1, of = f & 1;
      const int o = of * 16 + (lw & 15);
      const int cc = g * 32 + (lw >> 4) * 8 + half * 4;
      bf16x4 w4;
      #pragma unroll
      for (int j = 0; j < 4; ++j)
        w4[j] = (__bf16)W[((size_t)o * 224 + cc + j) * 3 + kt];
      *(bf16x4*)(Ws + idx * 8) = w4;
    }
    __syncthreads();

    bf16x8 a8[13];
    const int gbase = q * 8 * 128 + (wave * 16 + r16) * 2;
    #pragma unroll
    for (int l = 0; l < 13; ++l) {
      bf16x8 a;
      #pragma unroll
      for (int j = 0; j < 8; ++j)
        a[j] = *(const __bf16*)(sm + l * 4096 + gbase + j * 128);
      a8[l] = a;
    }
    bf16x8 wf[6];
    #pragma unroll
    for (int f = 0; f < 6; ++f)
      wf[f] = *(const bf16x8*)(Ws + (f * 64 + lane) * 16);

    #pragma unroll
    for (int kt = 0; kt < 3; ++kt)
      #pragma unroll
      for (int of = 0; of < 2; ++of)
        #pragma unroll
        for (int t = 0; t < 11; ++t)
          acc[t][of] = __builtin_amdgcn_mfma_f32_16x16x32_bf16(a8[t + kt], wf[kt * 2 + of], acc[t][of], 0, 0, 0);
  }

  float* Ds = (float*)sm;
  const int o16 = lane & 15;
  for (int p = 0; p < 2; ++p) {
    __syncthreads();
    #pragma unroll
    for (int t = 0; t < 11; ++t) {
      const int vbase = wave * 16 + q * 4;
      #pragma unroll
      for (int rg = 0; rg < 4; ++rg)
        Ds[o16 * 708 + (vbase + rg) * 11 + t] = acc[t][p][rg];
    }
    __syncthreads();
    for (int i = 0; i < 11; ++i) {
      const int cg = tid + i * 256;
      const int oo = cg / 176, ch = cg - oo * 176;
      f32x4 v4 = *(const f32x4*)(Ds + oo * 708 + ch * 4);
      const float bo = bias[p * 16 + oo];
      v4[0] += bo; v4[1] += bo; v4[2] += bo; v4[3] += bo;
      float* yp = y + (((size_t)n * 32 + p * 16 + oo) * 512 + vt * 64) * 11 + ch * 4;
      *(f32x4*)yp = v4;
    }
  }
}

extern "C" void kernel_launch(void* const* d_in, const int* in_sizes, int n_in,
                              void* d_out, int out_size, void* d_ws, size_t ws_size,
                              hipStream_t stream) {
  (void)in_sizes; (void)n_in; (void)out_size; (void)ws_size;
  const float* x = (const float*)d_in[0];
  const float* A = (const float*)d_in[1];
  const float* W = (const float*)d_in[2];
  const float* b = (const float*)d_in[3];
  float* y = (float*)d_out;

  // ws: Xv2 (27.3 MB) + Y1 x3 (81.8) + Y2 x3 (81.8) + Ab (1.6) = 192.4 MB (known-good)
  char* ws = (char*)d_ws;
  const size_t SXB = (size_t)SXE * 2;
  __bf16* Xv2 = (__bf16*)ws;
  __bf16* Y1  = (__bf16*)(ws + SXB);
  __bf16* Y2  = (__bf16*)(ws + 4 * SXB);
  __bf16* Ab  = (__bf16*)(ws + 7 * SXB);

  cast_A<<<dim3(768), 256, 0, stream>>>(A, Ab);
  prep_x<<<dim3(32, 64), 256, 0, stream>>>(x, Xv2);
  // grid = 104 bx * 2 by * 3 s = 624 = 8 * 78 (bijective swizzle; cpx = 78); 128KB dynamic LDS
  gemm_bf16<<<dim3(624), 512, 131072, stream>>>(Ab, Xv2, Y1, 0, (size_t)SXE, 78);
  gemm_bf16<<<dim3(624), 512, 131072, stream>>>(Ab, Y1, Y2, (size_t)SXE, (size_t)SXE, 78);
  conv_kernel<<<dim3(8, 64), 256, 0, stream>>>(Xv2, Y1, Y2, W, b, y);
}